// Round 16
// baseline (192.861 us; speedup 1.0000x reference)
//
#include <hip/hip_runtime.h>
#include <hip/hip_bf16.h>

#define NBATCH 32
#define NG 1024
#define DM 256

typedef short bf16x8 __attribute__((ext_vector_type(8)));
typedef float f32x4 __attribute__((ext_vector_type(4)));
typedef unsigned short u16x4 __attribute__((ext_vector_type(4)));
typedef unsigned short u16x8 __attribute__((ext_vector_type(8)));

static __device__ __forceinline__ unsigned short f2bf(float f) {
    __hip_bfloat16 h = __float2bfloat16(f);
    return *reinterpret_cast<unsigned short*>(&h);
}
static __device__ __forceinline__ float bf2f(unsigned short u) {
    unsigned int x = ((unsigned int)u) << 16;
    return *reinterpret_cast<float*>(&x);
}

// async global->LDS, 16B per lane. LDS dest wave-uniform (HW adds lane*16);
// global source is per-lane.
static __device__ __forceinline__ void gload16(const void* g, void* l) {
    __builtin_amdgcn_global_load_lds(
        (const __attribute__((address_space(1))) unsigned int*)g,
        (__attribute__((address_space(3))) unsigned int*)l, 16, 0, 0);
}

// counted-vmcnt barrier pairs (T4) for the proj kernels
static __device__ __forceinline__ void wait_vm8_bar() {
    asm volatile("s_waitcnt vmcnt(8)" ::: "memory");
    asm volatile("s_barrier" ::: "memory");
    __builtin_amdgcn_sched_barrier(0);
}
static __device__ __forceinline__ void wait_vm0_bar() {
    asm volatile("s_waitcnt vmcnt(0)" ::: "memory");
    asm volatile("s_barrier" ::: "memory");
    __builtin_amdgcn_sched_barrier(0);
}
static __device__ __forceinline__ void bar_only() {
    asm volatile("s_barrier" ::: "memory");
}

// ---------------------------------------------------------------------------
// Kernel W: pack Wq|Wk|Wv (f32 [e][d]) -> bf16 Wb[3][256][256]. L2-resident.
// ---------------------------------------------------------------------------
__global__ __launch_bounds__(256) void wpack_kernel(
    const float* __restrict__ Wq, const float* __restrict__ Wk,
    const float* __restrict__ Wv, unsigned short* __restrict__ Wb)
{
    const int i4 = (blockIdx.x * 256 + threadIdx.x) * 4;   // grid 192
    const int t = i4 >> 16;
    const int off = i4 & 65535;
    const float* src = (t == 0) ? Wq : (t == 1) ? Wk : Wv;
    float4 v = *(const float4*)(src + off);
    *(u16x4*)(Wb + i4) = (u16x4){ f2bf(v.x), f2bf(v.y), f2bf(v.z), f2bf(v.w) };
}

// ---------------------------------------------------------------------------
// Kernel X: q|k|v f32 -> bf16 stream convert, one launch. grid 12288.
// ---------------------------------------------------------------------------
__global__ __launch_bounds__(256) void conv3_kernel(
    const float* __restrict__ q, const float* __restrict__ k,
    const float* __restrict__ v, unsigned short* __restrict__ Xb)
{
    const int sel = blockIdx.x >> 12;
    const float* src = (sel == 0) ? q : (sel == 1) ? k : v;
    const size_t i8 = (((size_t)(blockIdx.x & 4095)) * 256 + threadIdx.x) * 8;
    float4 a = *(const float4*)(src + i8);
    float4 b = *(const float4*)(src + i8 + 4);
    *(u16x8*)(Xb + (size_t)sel * NBATCH * NG * DM + i8) =
        (u16x8){ f2bf(a.x), f2bf(a.y), f2bf(a.z), f2bf(a.w),
                 f2bf(b.x), f2bf(b.y), f2bf(b.z), f2bf(b.w) };
}

// ---------------------------------------------------------------------------
// Kernel B: exp_A = bf16(exp2(sc * dist)), full batch. grid 16384.
// ---------------------------------------------------------------------------
__global__ __launch_bounds__(256) void exp_kernel(
    const float* __restrict__ dist, unsigned short* __restrict__ ea,
    const float* __restrict__ alpha_raw)
{
    const float alpha = log1pf(__expf(alpha_raw[0])) + 1e-6f;
    const float sc = -alpha * 10.0f * 1.44269504088896f;
    const size_t i8 = ((size_t)blockIdx.x * 256 + threadIdx.x) * 8;
    float4 v0 = *(const float4*)(dist + i8);
    float4 v1 = *(const float4*)(dist + i8 + 4);
    u16x8 o = { f2bf(exp2f(sc * v0.x)), f2bf(exp2f(sc * v0.y)),
                f2bf(exp2f(sc * v0.z)), f2bf(exp2f(sc * v0.w)),
                f2bf(exp2f(sc * v1.x)), f2bf(exp2f(sc * v1.y)),
                f2bf(exp2f(sc * v1.z)), f2bf(exp2f(sc * v1.w)) };
    *(u16x8*)(ea + i8) = o;
}

// ---------------------------------------------------------------------------
// Kernel Q: qb = bf16(Xq @ Wq^T + bq)  (pre-sigmoid; attn applies sigmoid).
// dbuf + counted-vmcnt (T4), proven structure.
// ---------------------------------------------------------------------------
__global__ __launch_bounds__(256) void projq_kernel(
    const unsigned short* __restrict__ Xq,   // [32768][256] bf16
    const unsigned short* __restrict__ Wb,   // [256][256] bf16 (Wq)
    const float* __restrict__ bq,
    unsigned short* __restrict__ qb)         // [32768][256] bf16
{
    __shared__ __align__(128) unsigned short lds[2][2][128 * 64];

    const int bid = blockIdx.x;
    const int mt = bid >> 1, nt = bid & 1;
    const int tid = threadIdx.x;
    const int w = tid >> 6, lane = tid & 63;
    const int wm = w >> 1, wn = w & 1;
    const int l15 = lane & 15, lhi = lane >> 4;
    const int lr = lane >> 3, sl = lane & 7;
    const int sp = sl ^ lr;

    const char* Abase = (const char*)(Xq + (size_t)mt * 128 * 256);
    const char* Wbase = (const char*)(Wb + (size_t)nt * 128 * 256);

    f32x4 acc[4][4];
    #pragma unroll
    for (int mi = 0; mi < 4; ++mi)
        #pragma unroll
        for (int ni = 0; ni < 4; ++ni)
            acc[mi][ni] = (f32x4){0.f, 0.f, 0.f, 0.f};

    auto STAGE = [&](int buf, int t) {
        #pragma unroll
        for (int i = 0; i < 4; ++i) {
            const int r = w * 32 + i * 8 + lr;
            gload16(Abase + (size_t)r * 512 + t * 128 + sp * 16,
                    (char*)&lds[buf][0][0] + w * 4096 + i * 1024);
            gload16(Wbase + (size_t)r * 512 + t * 128 + sp * 16,
                    (char*)&lds[buf][1][0] + w * 4096 + i * 1024);
        }
    };

    STAGE(0, 0);
    int cur = 0;
    for (int t = 0; t < 4; ++t) {
        if (t < 3) { STAGE(cur ^ 1, t + 1); wait_vm8_bar(); }
        else       { wait_vm0_bar(); }
        const char* Ab = (const char*)&lds[cur][0][0];
        const char* Bb = (const char*)&lds[cur][1][0];
        #pragma unroll
        for (int kk = 0; kk < 2; ++kk) {
            bf16x8 af[4], bfr[4];
            #pragma unroll
            for (int mi = 0; mi < 4; ++mi) {
                const int tr = wm * 64 + mi * 16 + l15;
                af[mi] = *(const bf16x8*)(Ab + ((tr * 128 + kk * 64 + lhi * 16) ^ ((tr & 7) << 4)));
            }
            #pragma unroll
            for (int ni = 0; ni < 4; ++ni) {
                const int tr = wn * 64 + ni * 16 + l15;
                bfr[ni] = *(const bf16x8*)(Bb + ((tr * 128 + kk * 64 + lhi * 16) ^ ((tr & 7) << 4)));
            }
            #pragma unroll
            for (int mi = 0; mi < 4; ++mi)
                #pragma unroll
                for (int ni = 0; ni < 4; ++ni)
                    acc[mi][ni] = __builtin_amdgcn_mfma_f32_16x16x32_bf16(
                        af[mi], bfr[ni], acc[mi][ni], 0, 0, 0);
        }
        bar_only();
        cur ^= 1;
    }

    #pragma unroll
    for (int ni = 0; ni < 4; ++ni) {
        const int c = nt * 128 + wn * 64 + ni * 16 + l15;
        const float bqs = bq[c];
        #pragma unroll
        for (int mi = 0; mi < 4; ++mi)
            #pragma unroll
            for (int r = 0; r < 4; ++r) {
                const size_t R = (size_t)mt * 128 + wm * 64 + mi * 16 + lhi * 4 + r;
                qb[R * DM + c] = f2bf(acc[mi][ni][r] + bqs);
            }
    }
}

// ---------------------------------------------------------------------------
// Kernel KV: k, v projections fused (row = [k 64B | v 64B]); dbuf + T4.
// Pt rows 2c/2c+1 = exp(k)*v / exp(k).
// ---------------------------------------------------------------------------
__global__ __launch_bounds__(256) void projkv_kernel(
    const unsigned short* __restrict__ Xk,
    const unsigned short* __restrict__ Xv,
    const unsigned short* __restrict__ Wkb,
    const unsigned short* __restrict__ Wvb,
    const float* __restrict__ bk, const float* __restrict__ bv,
    unsigned short* __restrict__ Pt)
{
    __shared__ __align__(128) unsigned short lds[2][2][128 * 64];

    const int bid = blockIdx.x;
    const int mt = bid >> 1, nt = bid & 1;
    const int tid = threadIdx.x;
    const int w = tid >> 6, lane = tid & 63;
    const int wm = w >> 1, wn = w & 1;
    const int l15 = lane & 15, lhi = lane >> 4;
    const int lr = lane >> 3, sl = lane & 7;
    const int sp = sl ^ lr;
    const int g16 = (sp & 3) * 16;

    f32x4 kacc[4][4], vacc[4][4];
    #pragma unroll
    for (int mi = 0; mi < 4; ++mi)
        #pragma unroll
        for (int ni = 0; ni < 4; ++ni) {
            kacc[mi][ni] = (f32x4){0.f, 0.f, 0.f, 0.f};
            vacc[mi][ni] = (f32x4){0.f, 0.f, 0.f, 0.f};
        }

    auto STAGE = [&](int buf, int t) {
        #pragma unroll
        for (int i = 0; i < 4; ++i) {
            const int r = w * 32 + i * 8 + lr;
            const char* asrc = (sp < 4 ? (const char*)Xk : (const char*)Xv)
                               + (size_t)(mt * 128 + r) * 512 + t * 64 + g16;
            gload16(asrc, (char*)&lds[buf][0][0] + w * 4096 + i * 1024);
            const char* wsrc = (sp < 4 ? (const char*)Wkb : (const char*)Wvb)
                               + (size_t)(nt * 128 + r) * 512 + t * 64 + g16;
            gload16(wsrc, (char*)&lds[buf][1][0] + w * 4096 + i * 1024);
        }
    };

    STAGE(0, 0);
    int cur = 0;
    for (int t = 0; t < 8; ++t) {
        if (t < 7) { STAGE(cur ^ 1, t + 1); wait_vm8_bar(); }
        else       { wait_vm0_bar(); }
        const char* Ab = (const char*)&lds[cur][0][0];
        const char* Bb = (const char*)&lds[cur][1][0];
        bf16x8 kaf[4], vaf[4], kbf[4], vbf[4];
        #pragma unroll
        for (int mi = 0; mi < 4; ++mi) {
            const int tr = wm * 64 + mi * 16 + l15;
            const int sw = (tr & 7) << 4;
            kaf[mi] = *(const bf16x8*)(Ab + ((tr * 128 + lhi * 16) ^ sw));
            vaf[mi] = *(const bf16x8*)(Ab + ((tr * 128 + 64 + lhi * 16) ^ sw));
        }
        #pragma unroll
        for (int ni = 0; ni < 4; ++ni) {
            const int tr = wn * 64 + ni * 16 + l15;
            const int sw = (tr & 7) << 4;
            kbf[ni] = *(const bf16x8*)(Bb + ((tr * 128 + lhi * 16) ^ sw));
            vbf[ni] = *(const bf16x8*)(Bb + ((tr * 128 + 64 + lhi * 16) ^ sw));
        }
        #pragma unroll
        for (int mi = 0; mi < 4; ++mi)
            #pragma unroll
            for (int ni = 0; ni < 4; ++ni) {
                kacc[mi][ni] = __builtin_amdgcn_mfma_f32_16x16x32_bf16(
                    kaf[mi], kbf[ni], kacc[mi][ni], 0, 0, 0);
                vacc[mi][ni] = __builtin_amdgcn_mfma_f32_16x16x32_bf16(
                    vaf[mi], vbf[ni], vacc[mi][ni], 0, 0, 0);
            }
        bar_only();
        cur ^= 1;
    }

    const int b = (mt * 128) >> 10;
    const int kb0 = (mt * 128) & 1023;
    #pragma unroll
    for (int ni = 0; ni < 4; ++ni) {
        const int c = nt * 128 + wn * 64 + ni * 16 + l15;
        const float bks = bk[c], bvs = bv[c];
        #pragma unroll
        for (int mi = 0; mi < 4; ++mi) {
            unsigned short p1[4], p2[4];
            #pragma unroll
            for (int r = 0; r < 4; ++r) {
                const float ek = __expf(kacc[mi][ni][r] + bks);
                const float vv = vacc[mi][ni][r] + bvs;
                p1[r] = f2bf(ek * vv);
                p2[r] = f2bf(ek);
            }
            const int kidx = kb0 + wm * 64 + mi * 16 + lhi * 4;
            *(u16x4*)&Pt[((size_t)b * 512 + 2 * c    ) * NG + kidx] =
                (u16x4){p1[0], p1[1], p1[2], p1[3]};
            *(u16x4*)&Pt[((size_t)b * 512 + 2 * c + 1) * NG + kidx] =
                (u16x4){p2[0], p2[1], p2[2], p2[3]};
        }
    }
}

// ---------------------------------------------------------------------------
// Kernel C: out = sigmoid(q) * (num/den). m201-style 8-PHASE schedule.
// 256x256 tile, BK=64 K-tiles (16 total -> 8 iters x 2 K-tiles), 8 waves
// (2M x 4N), LDS 128 KB = [2 buf][A,B][2 halves][128 rows x 128 B].
// Per K-tile: B-strip (8 b128) read ONCE (ph1/ph5, held in regs); A-lo at
// ph1/ph5, A-hi at ph3/ph7 -> B halves free after ph1, A after ph3.
// Stage 1 unit (16 KB, 2 gload16/thread) per phase:
//   ph1: b1.A1<-T2i+1  ph2: b0.B0<-T2i+2  ph3: b0.B1  ph4: b0.A0
//   ph5: b0.A1         ph6: b1.B0<-T2i+3  ph7: b1.B1  ph8: b1.A0
// WAR: every unit staged >=1 end-barrier after its last reader (verified).
// RAW: vmcnt(6) at ph4/ph8 end + barrier vouches all 8 read points
// (3 units in flight, the m201/m218 constant). lgkmcnt(0)+sched_barrier(0)
// at ds_read phases only (rule 18); setprio(1) around each 16-MFMA quadrant.
// Prologue stages T0+T1 (vmcnt 0); iter-0 ph1 re-stages T1.A1 (same bytes,
// harmless); tail wraps t&15 (staged but never read).
// r13's proven XOR swizzle on 128B rows (0 conflicts, refcheck'd).
// grid 256 = 32b x 4m x 2n, 1 block/CU, XCD-chunked.
// ---------------------------------------------------------------------------
__global__ __launch_bounds__(512, 2) void attn_kernel(
    const unsigned short* __restrict__ ea,
    const unsigned short* __restrict__ Pt,
    const unsigned short* __restrict__ qb,
    float* __restrict__ out)
{
    __shared__ __align__(128) char lds[2][2][2][128 * 128];  // [buf][op][half]

    const int bid = blockIdx.x;
    const int l = (bid & 7) * 32 + (bid >> 3);   // XCD-chunked, bijective
    const int b = l >> 3;          // 0..31
    const int m = (l >> 1) & 3;    // 0..3
    const int n = l & 1;           // 0..1

    const int tid = threadIdx.x;
    const int w = tid >> 6, lane = tid & 63;
    const int wm = w >> 2, wn = w & 3;           // wave grid 2x4
    const int l15 = lane & 15, lhi = lane >> 4;

    // staging mapping: per unit (128 rows x 128B), 2 rounds of 64 rows
    const int srow = tid >> 3;                   // 0..63
    const int sg = (tid & 7) ^ (srow & 7);       // inverse-swizzled granule

    const char* Abase = (const char*)(ea + ((size_t)b * NG + m * 256) * NG);
    const char* Bbase = (const char*)(Pt + ((size_t)b * 512 + n * 256) * NG);

    f32x4 acc[8][4];
    #pragma unroll
    for (int mi = 0; mi < 8; ++mi)
        #pragma unroll
        for (int ni = 0; ni < 4; ++ni)
            acc[mi][ni] = (f32x4){0.f, 0.f, 0.f, 0.f};

    bf16x8 af[8];    // A regs: [mi-in-quad 0..3][kk 0..1]
    bf16x8 bfr[8];   // B regs: [ni 0..3][kk 0..1]

    // stage one 16 KB unit: (buf, op 0=A/1=B, half h) <- K-tile t
    auto UNIT = [&](int buf, int op, int h, int t) {
        const char* S = op ? Bbase : Abase;
        char* D = &lds[buf][op][h][0] + w * 1024;
        #pragma unroll
        for (int j = 0; j < 2; ++j) {
            const int r = h * 128 + j * 64 + srow;
            gload16(S + (size_t)r * 2048 + (size_t)(t & 15) * 128 + sg * 16,
                    D + j * 8192);
        }
    };
    auto RD_A = [&](int buf, int mh) {
        const char* Ah = &lds[buf][0][wm][0];
        #pragma unroll
        for (int q = 0; q < 4; ++q) {
            const int row = (mh * 4 + q) * 16 + l15;
            #pragma unroll
            for (int kk = 0; kk < 2; ++kk)
                af[q * 2 + kk] = *(const bf16x8*)(
                    Ah + ((row * 128 + kk * 64 + lhi * 16) ^ ((row & 7) << 4)));
        }
    };
    auto RD_B = [&](int buf) {
        const char* Bh = &lds[buf][1][wn >> 1][0];
        #pragma unroll
        for (int ni = 0; ni < 4; ++ni) {
            const int row = (wn & 1) * 64 + ni * 16 + l15;
            #pragma unroll
            for (int kk = 0; kk < 2; ++kk)
                bfr[ni * 2 + kk] = *(const bf16x8*)(
                    Bh + ((row * 128 + kk * 64 + lhi * 16) ^ ((row & 7) << 4)));
        }
    };
    auto QMFMA = [&](int mh, int nh) {
        __builtin_amdgcn_s_setprio(1);
        #pragma unroll
        for (int q = 0; q < 4; ++q)
            #pragma unroll
            for (int nj = 0; nj < 2; ++nj)
                #pragma unroll
                for (int kk = 0; kk < 2; ++kk)
                    acc[mh * 4 + q][nh * 2 + nj] = __builtin_amdgcn_mfma_f32_16x16x32_bf16(
                        af[q * 2 + kk], bfr[(nh * 2 + nj) * 2 + kk],
                        acc[mh * 4 + q][nh * 2 + nj], 0, 0, 0);
        __builtin_amdgcn_s_setprio(0);
    };
    auto LGK0 = [&]() {
        asm volatile("s_waitcnt lgkmcnt(0)" ::: "memory");
        __builtin_amdgcn_sched_barrier(0);
    };

    // prologue: T0 -> buf0, T1 -> buf1 (all 4 units each)
    #pragma unroll
    for (int u = 0; u < 4; ++u) {
        UNIT(0, u >> 1, u & 1, 0);
        UNIT(1, u >> 1, u & 1, 1);
    }
    asm volatile("s_waitcnt vmcnt(0)" ::: "memory");
    __builtin_amdgcn_s_barrier();

    for (int i = 0; i < 8; ++i) {
        const int Tb = 2 * i + 1;
        // ph1: quadrant (0,0) of T2i (buf0)
        RD_A(0, 0); RD_B(0);
        UNIT(1, 0, 1, Tb);                 // b1.A1 <- T2i+1
        __builtin_amdgcn_s_barrier();
        LGK0();
        QMFMA(0, 0);
        __builtin_amdgcn_s_barrier();
        // ph2: (0,1)
        UNIT(0, 1, 0, Tb + 1);             // b0.B0 <- T2i+2
        __builtin_amdgcn_s_barrier();
        QMFMA(0, 1);
        __builtin_amdgcn_s_barrier();
        // ph3: (1,0)
        RD_A(0, 1);
        UNIT(0, 1, 1, Tb + 1);             // b0.B1
        __builtin_amdgcn_s_barrier();
        LGK0();
        QMFMA(1, 0);
        __builtin_amdgcn_s_barrier();
        // ph4: (1,1)
        UNIT(0, 0, 0, Tb + 1);             // b0.A0
        __builtin_amdgcn_s_barrier();
        QMFMA(1, 1);
        asm volatile("s_waitcnt vmcnt(6)" ::: "memory");
        __builtin_amdgcn_s_barrier();
        // ph5: quadrant (0,0) of T2i+1 (buf1)
        RD_A(1, 0); RD_B(1);
        UNIT(0, 0, 1, Tb + 1);             // b0.A1
        __builtin_amdgcn_s_barrier();
        LGK0();
        QMFMA(0, 0);
        __builtin_amdgcn_s_barrier();
        // ph6: (0,1)
        UNIT(1, 1, 0, Tb + 2);             // b1.B0 <- T2i+3
        __builtin_amdgcn_s_barrier();
        QMFMA(0, 1);
        __builtin_amdgcn_s_barrier();
        // ph7: (1,0)
        RD_A(1, 1);
        UNIT(1, 1, 1, Tb + 2);             // b1.B1
        __builtin_amdgcn_s_barrier();
        LGK0();
        QMFMA(1, 0);
        __builtin_amdgcn_s_barrier();
        // ph8: (1,1)
        UNIT(1, 0, 0, Tb + 2);             // b1.A0
        __builtin_amdgcn_s_barrier();
        QMFMA(1, 1);
        asm volatile("s_waitcnt vmcnt(6)" ::: "memory");
        __builtin_amdgcn_s_barrier();
    }

    asm volatile("s_waitcnt vmcnt(0)" ::: "memory");
    __builtin_amdgcn_s_barrier();

    // epilogue: even col = numerator, odd = denominator (same d); sigmoid(q)
    const int parity = lane & 1;
    #pragma unroll
    for (int mi = 0; mi < 8; ++mi)
        #pragma unroll
        for (int ni = 0; ni < 4; ++ni)
            #pragma unroll
            for (int r = 0; r < 4; ++r) {
                const float own = acc[mi][ni][r];
                const float other = __shfl_xor(own, 1, 64);
                if (!parity) {
                    const int colg = n * 256 + wn * 64 + ni * 16 + l15;   // even
                    const int d = colg >> 1;
                    const int rowg = m * 256 + wm * 128 + mi * 16 + lhi * 4 + r;
                    const size_t idx = ((size_t)b * NG + rowg) * DM + d;
                    const float q = bf2f(qb[idx]);
                    const float sig = 1.0f / (1.0f + __expf(-q));
                    out[idx] = sig * (own / (other + 1e-8f));
                }
            }
}

extern "C" void kernel_launch(void* const* d_in, const int* in_sizes, int n_in,
                              void* d_out, int out_size, void* d_ws, size_t ws_size,
                              hipStream_t stream) {
    const float* query = (const float*)d_in[0];
    const float* key_  = (const float*)d_in[1];
    const float* value = (const float*)d_in[2];
    const float* dist  = (const float*)d_in[3];
    const float* Wq = (const float*)d_in[4];
    const float* bq = (const float*)d_in[5];
    const float* Wk = (const float*)d_in[6];
    const float* bk = (const float*)d_in[7];
    const float* Wv = (const float*)d_in[8];
    const float* bv = (const float*)d_in[9];
    const float* alpha_raw = (const float*)d_in[10];
    float* out = (float*)d_out;

    // ws (512 MiB): Pt 32M | ea 64M | Xb 3x16.8M | qb 16.8M | Wb 384K
    unsigned short* Pt = (unsigned short*)d_ws;
    unsigned short* ea = Pt + (size_t)NBATCH * 512 * NG;
    unsigned short* Xb = ea + (size_t)NBATCH * NG * NG;
    const size_t XN = (size_t)NBATCH * NG * DM;
    unsigned short* qb = Xb + 3 * XN;
    unsigned short* Wb = qb + XN;

    wpack_kernel<<<dim3(192), dim3(256), 0, stream>>>(Wq, Wk, Wv, Wb);
    conv3_kernel<<<dim3(12288), dim3(256), 0, stream>>>(query, key_, value, Xb);

    projq_kernel<<<dim3(512), dim3(256), 0, stream>>>(Xb, Wb, bq, qb);
    projkv_kernel<<<dim3(512), dim3(256), 0, stream>>>(
        Xb + XN, Xb + 2 * XN, Wb + 65536, Wb + 131072, bk, bv, Pt);

    exp_kernel<<<dim3(16384), dim3(256), 0, stream>>>(dist, ea, alpha_raw);
    attn_kernel<<<dim3(256), dim3(512), 0, stream>>>(ea, Pt, qb, out);
}

// Round 17
// 173.319 us; speedup vs baseline: 1.1127x; 1.1127x over previous
//
#include <hip/hip_runtime.h>
#include <hip/hip_bf16.h>

#define NBATCH 32
#define NG 1024
#define DM 256

typedef short bf16x8 __attribute__((ext_vector_type(8)));
typedef float f32x4 __attribute__((ext_vector_type(4)));
typedef unsigned short u16x4 __attribute__((ext_vector_type(4)));
typedef unsigned short u16x8 __attribute__((ext_vector_type(8)));

static __device__ __forceinline__ unsigned short f2bf(float f) {
    __hip_bfloat16 h = __float2bfloat16(f);
    return *reinterpret_cast<unsigned short*>(&h);
}
static __device__ __forceinline__ float bf2f(unsigned short u) {
    unsigned int x = ((unsigned int)u) << 16;
    return *reinterpret_cast<float*>(&x);
}

// async global->LDS, 16B per lane. LDS dest wave-uniform (HW adds lane*16);
// global source is per-lane.
static __device__ __forceinline__ void gload16(const void* g, void* l) {
    __builtin_amdgcn_global_load_lds(
        (const __attribute__((address_space(1))) unsigned int*)g,
        (__attribute__((address_space(3))) unsigned int*)l, 16, 0, 0);
}

// counted-vmcnt barrier pairs (T4)
static __device__ __forceinline__ void wait_vm8_bar() {
    asm volatile("s_waitcnt vmcnt(8)" ::: "memory");
    asm volatile("s_barrier" ::: "memory");
    __builtin_amdgcn_sched_barrier(0);
}
static __device__ __forceinline__ void wait_vm4_bar() {
    asm volatile("s_waitcnt vmcnt(4)" ::: "memory");
    asm volatile("s_barrier" ::: "memory");
    __builtin_amdgcn_sched_barrier(0);
}
static __device__ __forceinline__ void wait_vm0_bar() {
    asm volatile("s_waitcnt vmcnt(0)" ::: "memory");
    asm volatile("s_barrier" ::: "memory");
    __builtin_amdgcn_sched_barrier(0);
}
static __device__ __forceinline__ void bar_only() {
    asm volatile("s_barrier" ::: "memory");
}

// ---------------------------------------------------------------------------
// Kernel P: merged prep — conv3 (blocks 0..12287) | exp (12288..28671) |
// wpack (28672..28863). All memory-bound elementwise; one launch.
// ---------------------------------------------------------------------------
__global__ __launch_bounds__(256) void prep_kernel(
    const float* __restrict__ q, const float* __restrict__ k,
    const float* __restrict__ v, const float* __restrict__ dist,
    const float* __restrict__ Wq, const float* __restrict__ Wk,
    const float* __restrict__ Wv, const float* __restrict__ alpha_raw,
    unsigned short* __restrict__ Xb, unsigned short* __restrict__ ea,
    unsigned short* __restrict__ Wb)
{
    const int bid = blockIdx.x;
    if (bid < 12288) {
        const int sel = bid >> 12;
        const float* src = (sel == 0) ? q : (sel == 1) ? k : v;
        const size_t i8 = (((size_t)(bid & 4095)) * 256 + threadIdx.x) * 8;
        float4 a = *(const float4*)(src + i8);
        float4 c = *(const float4*)(src + i8 + 4);
        *(u16x8*)(Xb + (size_t)sel * NBATCH * NG * DM + i8) =
            (u16x8){ f2bf(a.x), f2bf(a.y), f2bf(a.z), f2bf(a.w),
                     f2bf(c.x), f2bf(c.y), f2bf(c.z), f2bf(c.w) };
    } else if (bid < 28672) {
        const float alpha = log1pf(__expf(alpha_raw[0])) + 1e-6f;
        const float sc = -alpha * 10.0f * 1.44269504088896f;
        const size_t i8 = (((size_t)(bid - 12288)) * 256 + threadIdx.x) * 8;
        float4 v0 = *(const float4*)(dist + i8);
        float4 v1 = *(const float4*)(dist + i8 + 4);
        *(u16x8*)(ea + i8) =
            (u16x8){ f2bf(exp2f(sc * v0.x)), f2bf(exp2f(sc * v0.y)),
                     f2bf(exp2f(sc * v0.z)), f2bf(exp2f(sc * v0.w)),
                     f2bf(exp2f(sc * v1.x)), f2bf(exp2f(sc * v1.y)),
                     f2bf(exp2f(sc * v1.z)), f2bf(exp2f(sc * v1.w)) };
    } else {
        const int i4 = ((bid - 28672) * 256 + threadIdx.x) * 4;
        const int t = i4 >> 16;
        const int off = i4 & 65535;
        const float* src = (t == 0) ? Wq : (t == 1) ? Wk : Wv;
        float4 w4 = *(const float4*)(src + off);
        *(u16x4*)(Wb + i4) = (u16x4){ f2bf(w4.x), f2bf(w4.y), f2bf(w4.z), f2bf(w4.w) };
    }
}

// ---------------------------------------------------------------------------
// Kernel Q: qb = bf16(Xq @ Wq^T + bq)  (pre-sigmoid; attn applies sigmoid).
// dbuf + counted-vmcnt (T4), proven structure.
// ---------------------------------------------------------------------------
__global__ __launch_bounds__(256) void projq_kernel(
    const unsigned short* __restrict__ Xq,   // [32768][256] bf16
    const unsigned short* __restrict__ Wb,   // [256][256] bf16 (Wq)
    const float* __restrict__ bq,
    unsigned short* __restrict__ qb)         // [32768][256] bf16
{
    __shared__ __align__(128) unsigned short lds[2][2][128 * 64];

    const int bid = blockIdx.x;
    const int mt = bid >> 1, nt = bid & 1;
    const int tid = threadIdx.x;
    const int w = tid >> 6, lane = tid & 63;
    const int wm = w >> 1, wn = w & 1;
    const int l15 = lane & 15, lhi = lane >> 4;
    const int lr = lane >> 3, sl = lane & 7;
    const int sp = sl ^ lr;

    const char* Abase = (const char*)(Xq + (size_t)mt * 128 * 256);
    const char* Wbase = (const char*)(Wb + (size_t)nt * 128 * 256);

    f32x4 acc[4][4];
    #pragma unroll
    for (int mi = 0; mi < 4; ++mi)
        #pragma unroll
        for (int ni = 0; ni < 4; ++ni)
            acc[mi][ni] = (f32x4){0.f, 0.f, 0.f, 0.f};

    auto STAGE = [&](int buf, int t) {
        #pragma unroll
        for (int i = 0; i < 4; ++i) {
            const int r = w * 32 + i * 8 + lr;
            gload16(Abase + (size_t)r * 512 + t * 128 + sp * 16,
                    (char*)&lds[buf][0][0] + w * 4096 + i * 1024);
            gload16(Wbase + (size_t)r * 512 + t * 128 + sp * 16,
                    (char*)&lds[buf][1][0] + w * 4096 + i * 1024);
        }
    };

    STAGE(0, 0);
    int cur = 0;
    for (int t = 0; t < 4; ++t) {
        if (t < 3) { STAGE(cur ^ 1, t + 1); wait_vm8_bar(); }
        else       { wait_vm0_bar(); }
        const char* Ab = (const char*)&lds[cur][0][0];
        const char* Bb = (const char*)&lds[cur][1][0];
        #pragma unroll
        for (int kk = 0; kk < 2; ++kk) {
            bf16x8 af[4], bfr[4];
            #pragma unroll
            for (int mi = 0; mi < 4; ++mi) {
                const int tr = wm * 64 + mi * 16 + l15;
                af[mi] = *(const bf16x8*)(Ab + ((tr * 128 + kk * 64 + lhi * 16) ^ ((tr & 7) << 4)));
            }
            #pragma unroll
            for (int ni = 0; ni < 4; ++ni) {
                const int tr = wn * 64 + ni * 16 + l15;
                bfr[ni] = *(const bf16x8*)(Bb + ((tr * 128 + kk * 64 + lhi * 16) ^ ((tr & 7) << 4)));
            }
            #pragma unroll
            for (int mi = 0; mi < 4; ++mi)
                #pragma unroll
                for (int ni = 0; ni < 4; ++ni)
                    acc[mi][ni] = __builtin_amdgcn_mfma_f32_16x16x32_bf16(
                        af[mi], bfr[ni], acc[mi][ni], 0, 0, 0);
        }
        bar_only();
        cur ^= 1;
    }

    #pragma unroll
    for (int ni = 0; ni < 4; ++ni) {
        const int c = nt * 128 + wn * 64 + ni * 16 + l15;
        const float bqs = bq[c];
        #pragma unroll
        for (int mi = 0; mi < 4; ++mi)
            #pragma unroll
            for (int r = 0; r < 4; ++r) {
                const size_t R = (size_t)mt * 128 + wm * 64 + mi * 16 + lhi * 4 + r;
                qb[R * DM + c] = f2bf(acc[mi][ni][r] + bqs);
            }
    }
}

// ---------------------------------------------------------------------------
// Kernel KV: k, v projections fused (row = [k 64B | v 64B]); dbuf + T4.
// Pt rows 2c/2c+1 = exp(k)*v / exp(k).
// ---------------------------------------------------------------------------
__global__ __launch_bounds__(256) void projkv_kernel(
    const unsigned short* __restrict__ Xk,
    const unsigned short* __restrict__ Xv,
    const unsigned short* __restrict__ Wkb,
    const unsigned short* __restrict__ Wvb,
    const float* __restrict__ bk, const float* __restrict__ bv,
    unsigned short* __restrict__ Pt)
{
    __shared__ __align__(128) unsigned short lds[2][2][128 * 64];

    const int bid = blockIdx.x;
    const int mt = bid >> 1, nt = bid & 1;
    const int tid = threadIdx.x;
    const int w = tid >> 6, lane = tid & 63;
    const int wm = w >> 1, wn = w & 1;
    const int l15 = lane & 15, lhi = lane >> 4;
    const int lr = lane >> 3, sl = lane & 7;
    const int sp = sl ^ lr;
    const int g16 = (sp & 3) * 16;

    f32x4 kacc[4][4], vacc[4][4];
    #pragma unroll
    for (int mi = 0; mi < 4; ++mi)
        #pragma unroll
        for (int ni = 0; ni < 4; ++ni) {
            kacc[mi][ni] = (f32x4){0.f, 0.f, 0.f, 0.f};
            vacc[mi][ni] = (f32x4){0.f, 0.f, 0.f, 0.f};
        }

    auto STAGE = [&](int buf, int t) {
        #pragma unroll
        for (int i = 0; i < 4; ++i) {
            const int r = w * 32 + i * 8 + lr;
            const char* asrc = (sp < 4 ? (const char*)Xk : (const char*)Xv)
                               + (size_t)(mt * 128 + r) * 512 + t * 64 + g16;
            gload16(asrc, (char*)&lds[buf][0][0] + w * 4096 + i * 1024);
            const char* wsrc = (sp < 4 ? (const char*)Wkb : (const char*)Wvb)
                               + (size_t)(nt * 128 + r) * 512 + t * 64 + g16;
            gload16(wsrc, (char*)&lds[buf][1][0] + w * 4096 + i * 1024);
        }
    };

    STAGE(0, 0);
    int cur = 0;
    for (int t = 0; t < 8; ++t) {
        if (t < 7) { STAGE(cur ^ 1, t + 1); wait_vm8_bar(); }
        else       { wait_vm0_bar(); }
        const char* Ab = (const char*)&lds[cur][0][0];
        const char* Bb = (const char*)&lds[cur][1][0];
        bf16x8 kaf[4], vaf[4], kbf[4], vbf[4];
        #pragma unroll
        for (int mi = 0; mi < 4; ++mi) {
            const int tr = wm * 64 + mi * 16 + l15;
            const int sw = (tr & 7) << 4;
            kaf[mi] = *(const bf16x8*)(Ab + ((tr * 128 + lhi * 16) ^ sw));
            vaf[mi] = *(const bf16x8*)(Ab + ((tr * 128 + 64 + lhi * 16) ^ sw));
        }
        #pragma unroll
        for (int ni = 0; ni < 4; ++ni) {
            const int tr = wn * 64 + ni * 16 + l15;
            const int sw = (tr & 7) << 4;
            kbf[ni] = *(const bf16x8*)(Bb + ((tr * 128 + lhi * 16) ^ sw));
            vbf[ni] = *(const bf16x8*)(Bb + ((tr * 128 + 64 + lhi * 16) ^ sw));
        }
        #pragma unroll
        for (int mi = 0; mi < 4; ++mi)
            #pragma unroll
            for (int ni = 0; ni < 4; ++ni) {
                kacc[mi][ni] = __builtin_amdgcn_mfma_f32_16x16x32_bf16(
                    kaf[mi], kbf[ni], kacc[mi][ni], 0, 0, 0);
                vacc[mi][ni] = __builtin_amdgcn_mfma_f32_16x16x32_bf16(
                    vaf[mi], vbf[ni], vacc[mi][ni], 0, 0, 0);
            }
        bar_only();
        cur ^= 1;
    }

    const int b = (mt * 128) >> 10;
    const int kb0 = (mt * 128) & 1023;
    #pragma unroll
    for (int ni = 0; ni < 4; ++ni) {
        const int c = nt * 128 + wn * 64 + ni * 16 + l15;
        const float bks = bk[c], bvs = bv[c];
        #pragma unroll
        for (int mi = 0; mi < 4; ++mi) {
            unsigned short p1[4], p2[4];
            #pragma unroll
            for (int r = 0; r < 4; ++r) {
                const float ek = __expf(kacc[mi][ni][r] + bks);
                const float vv = vacc[mi][ni][r] + bvs;
                p1[r] = f2bf(ek * vv);
                p2[r] = f2bf(ek);
            }
            const int kidx = kb0 + wm * 64 + mi * 16 + lhi * 4;
            *(u16x4*)&Pt[((size_t)b * 512 + 2 * c    ) * NG + kidx] =
                (u16x4){p1[0], p1[1], p1[2], p1[3]};
            *(u16x4*)&Pt[((size_t)b * 512 + 2 * c + 1) * NG + kidx] =
                (u16x4){p2[0], p2[1], p2[2], p2[3]};
        }
    }
}

// ---------------------------------------------------------------------------
// Kernel C: out = sigmoid(q) * (num/den). 128x128 tile, BK=32, 256 threads
// (4 waves 2x2), dbuf 32 KB LDS -> 4 BLOCKS/CU (launch_bounds(256,4)).
// Rationale: staging throughput scales with resident blocks (r7: 2/CU ->
// 7.4 TB/s vs r13: 1/CU -> 3.3 TB/s); 4/CU targets ~9-10 TB/s on 536 MB.
// Counted vmcnt(4) (4 loads/thread/tile); r12's proven 64B-row XOR swizzle:
//  - write: linear dest; per-lane source granule = (tid&3) ^ ((row>>1)&3)
//  - read:  addr = tr*64 + ((lhi ^ ((l15>>1)&3)) * 16)    (0 conflicts)
// grid 1024 = 32b x 8m x 4n, XCD-chunked.
// ---------------------------------------------------------------------------
__global__ __launch_bounds__(256, 4) void attn_kernel(
    const unsigned short* __restrict__ ea,
    const unsigned short* __restrict__ Pt,
    const unsigned short* __restrict__ qb,
    float* __restrict__ out)
{
    __shared__ __align__(128) char lds[2][2][8192];   // [buf][A/B][128 rows x 64B]

    const int bid = blockIdx.x;
    const int l = (bid & 7) * 128 + (bid >> 3);   // bijective (1024 % 8 == 0)
    const int b = l >> 5;
    const int m = (l >> 2) & 7;
    const int n = l & 3;

    const int tid = threadIdx.x;
    const int w = tid >> 6, lane = tid & 63;
    const int wm = w >> 1, wn = w & 1;
    const int l15 = lane & 15, lhi = lane >> 4;
    const int xv = (l15 >> 1) & 3;               // read-side swizzle XOR

    const int sr = tid >> 2;                     // staging row 0..63 (+64 rnd 2)
    const int sgl = tid & 3;                     // logical granule

    const char* Abase = (const char*)(ea + ((size_t)b * NG + m * 128) * NG);
    const char* Bbase = (const char*)(Pt + ((size_t)b * 512 + n * 128) * NG);

    f32x4 acc[4][4];
    #pragma unroll
    for (int mi = 0; mi < 4; ++mi)
        #pragma unroll
        for (int ni = 0; ni < 4; ++ni)
            acc[mi][ni] = (f32x4){0.f, 0.f, 0.f, 0.f};

    // stage K-step t (32 bf16 = 64B per row, 128 rows each op): 4 gload/thread
    auto STAGE = [&](int buf, int t) {
        #pragma unroll
        for (int j = 0; j < 2; ++j) {
            const int r = j * 64 + sr;
            const int sg = sgl ^ ((r >> 1) & 3);
            // wave w covers rows [j*64 + w*16, +16); dest wave-uniform
            gload16(Abase + (size_t)r * 2048 + t * 64 + sg * 16,
                    &lds[buf][0][0] + j * 4096 + w * 1024);
            gload16(Bbase + (size_t)r * 2048 + t * 64 + sg * 16,
                    &lds[buf][1][0] + j * 4096 + w * 1024);
        }
    };

    STAGE(0, 0);
    int cur = 0;
    for (int t = 0; t < 32; ++t) {
        if (t < 31) { STAGE(cur ^ 1, t + 1); wait_vm4_bar(); }
        else        { wait_vm0_bar(); }
        const char* Ab = &lds[cur][0][0];
        const char* Bb = &lds[cur][1][0];
        __builtin_amdgcn_s_setprio(1);
        bf16x8 af[4], bfr[4];
        #pragma unroll
        for (int mi = 0; mi < 4; ++mi) {
            const int tr = wm * 64 + mi * 16 + l15;
            af[mi] = *(const bf16x8*)(Ab + tr * 64 + ((lhi ^ xv) * 16));
        }
        #pragma unroll
        for (int ni = 0; ni < 4; ++ni) {
            const int tr = wn * 64 + ni * 16 + l15;
            bfr[ni] = *(const bf16x8*)(Bb + tr * 64 + ((lhi ^ xv) * 16));
        }
        #pragma unroll
        for (int mi = 0; mi < 4; ++mi)
            #pragma unroll
            for (int ni = 0; ni < 4; ++ni)
                acc[mi][ni] = __builtin_amdgcn_mfma_f32_16x16x32_bf16(
                    af[mi], bfr[ni], acc[mi][ni], 0, 0, 0);
        __builtin_amdgcn_s_setprio(0);
        bar_only();
        cur ^= 1;
    }

    // epilogue: even col = numerator, odd = denominator (same d); sigmoid(q)
    const int parity = lane & 1;
    #pragma unroll
    for (int mi = 0; mi < 4; ++mi)
        #pragma unroll
        for (int ni = 0; ni < 4; ++ni)
            #pragma unroll
            for (int r = 0; r < 4; ++r) {
                const float own = acc[mi][ni][r];
                const float other = __shfl_xor(own, 1, 64);
                if (!parity) {
                    const int colg = n * 128 + wn * 64 + ni * 16 + l15;   // even
                    const int d = colg >> 1;
                    const int rowg = m * 128 + wm * 64 + mi * 16 + lhi * 4 + r;
                    const size_t idx = ((size_t)b * NG + rowg) * DM + d;
                    const float qv = bf2f(qb[idx]);
                    const float sig = 1.0f / (1.0f + __expf(-qv));
                    out[idx] = sig * (own / (other + 1e-8f));
                }
            }
}

extern "C" void kernel_launch(void* const* d_in, const int* in_sizes, int n_in,
                              void* d_out, int out_size, void* d_ws, size_t ws_size,
                              hipStream_t stream) {
    const float* query = (const float*)d_in[0];
    const float* key_  = (const float*)d_in[1];
    const float* value = (const float*)d_in[2];
    const float* dist  = (const float*)d_in[3];
    const float* Wq = (const float*)d_in[4];
    const float* bq = (const float*)d_in[5];
    const float* Wk = (const float*)d_in[6];
    const float* bk = (const float*)d_in[7];
    const float* Wv = (const float*)d_in[8];
    const float* bv = (const float*)d_in[9];
    const float* alpha_raw = (const float*)d_in[10];
    float* out = (float*)d_out;

    // ws (512 MiB): Pt 32M | ea 64M | Xb 3x16.8M | qb 16.8M | Wb 384K
    unsigned short* Pt = (unsigned short*)d_ws;
    unsigned short* ea = Pt + (size_t)NBATCH * 512 * NG;
    unsigned short* Xb = ea + (size_t)NBATCH * NG * NG;
    const size_t XN = (size_t)NBATCH * NG * DM;
    unsigned short* qb = Xb + 3 * XN;
    unsigned short* Wb = qb + XN;

    prep_kernel<<<dim3(28864), dim3(256), 0, stream>>>(
        query, key_, value, dist, Wq, Wk, Wv, alpha_raw, Xb, ea, Wb);

    projq_kernel<<<dim3(512), dim3(256), 0, stream>>>(Xb, Wb, bq, qb);
    projkv_kernel<<<dim3(512), dim3(256), 0, stream>>>(
        Xb + XN, Xb + 2 * XN, Wb + 65536, Wb + 131072, bk, bv, Pt);

    attn_kernel<<<dim3(1024), dim3(256), 0, stream>>>(ea, Pt, qb, out);
}